// Round 1
// baseline (12322.311 us; speedup 1.0000x reference)
//
#include <hip/hip_runtime.h>

typedef unsigned short ushort_t;
typedef __bf16 bf16x8 __attribute__((ext_vector_type(8)));
typedef float f32x4 __attribute__((ext_vector_type(4)));

#define T_STEPS 512
#define BATCH 64
#define HDIM 1024
#define CHUNK 32                 // steps per gate-precompute chunk
#define NCHUNK (T_STEPS / CHUNK) // 16
#define MCH (CHUNK * BATCH)      // 2048 rows per chunk GEMM
#define OUTS_ELEMS 33554432ULL
#define NWG 128                  // persistent WGs; 1/CU by LDS => co-residency guaranteed

// ---- LDS carve for lstm_chunk (dynamic, 150 KiB) ----
#define WS_BYTES   65536                       // W_h slice: 32 vc x 1024 k bf16, XOR-swizzled
#define HQ_BYTES   32768                       // h quarter: 64 b x 256 k bf16, XOR-swizzled
#define S_STRIDE   36                          // padded fp32 row stride (bank spread)
#define S_BYTES    (2 * 64 * S_STRIDE * 4)     // 2 kg-partials x 64 b x 36 = 18432
#define GG_BYTES   (64 * 32 * 2)               // gate-precompute tile 4096
#define SMEM_BYTES (WS_BYTES + 2 * HQ_BYTES + S_BYTES + GG_BYTES)  // 153600 <= 163840

__device__ __forceinline__ ushort_t f2bf(float f) {
    union { unsigned int i; float f; } v;
    v.f = f;
    unsigned int x = v.i;
    unsigned int r = (x + 0x7FFFu + ((x >> 16) & 1u)) >> 16;
    return (ushort_t)r;
}

__device__ __forceinline__ float bf2f(ushort_t u) {
    union { unsigned int i; float f; } v;
    v.i = ((unsigned int)u) << 16;
    return v.f;
}

struct Ptr8 { const float* p[8]; };
struct Ptr4 { const float* p[4]; };

// ---------------------------------------------------------------------------
// Transpose+convert 8 fp32 weight matrices [1024 k][1024 n] -> bf16 [1024 n][1024 k]
// ---------------------------------------------------------------------------
__global__ __launch_bounds__(256) void transpose8(Ptr8 in, ushort_t* __restrict__ out) {
    __shared__ ushort_t tile[64][65];
    int z = blockIdx.z;
    const float* src = in.p[z];
    ushort_t* dst = out + (size_t)z * 1024 * 1024;
    int bx = blockIdx.x * 64;  // n base
    int by = blockIdx.y * 64;  // k base
    int t = threadIdx.x;
#pragma unroll
    for (int i = 0; i < 16; i++) {
        int lin = t + i * 256;
        int r = lin >> 6, c = lin & 63;
        tile[r][c] = f2bf(src[(size_t)(by + r) * 1024 + bx + c]);
    }
    __syncthreads();
#pragma unroll
    for (int i = 0; i < 16; i++) {
        int lin = t + i * 256;
        int r = lin >> 6, c = lin & 63;
        dst[(size_t)(bx + r) * 1024 + by + c] = tile[c][r];
    }
}

// ---------------------------------------------------------------------------
// Chunk GEMM: G[m][n'] = A[m][:] @ wt_x[n'][:] + bias   (fp32 acc, bf16 out)
// ---------------------------------------------------------------------------
#define BK 32
#define LDK 40

__global__ __launch_bounds__(256) void chunk_gemm(
    const float* __restrict__ A,
    const ushort_t* __restrict__ Wt,
    Ptr4 biases,
    ushort_t* __restrict__ G)            // [2048 m][4096 n']
{
    __shared__ ushort_t As[128 * LDK];
    __shared__ ushort_t Bs[128 * LDK];

    int n0 = blockIdx.x * 128;
    int m0 = blockIdx.y * 128;
    int t = threadIdx.x;
    int wave = t >> 6, lane = t & 63;
    int wm = (wave & 1) * 64, wn = (wave >> 1) * 64;
    int lrow = lane & 15, quad = lane >> 4;
    int lk = quad * 8;

    f32x4 acc[4][4] = {};

    for (int k0 = 0; k0 < 1024; k0 += BK) {
        __syncthreads();
#pragma unroll
        for (int i = 0; i < 4; i++) {
            int c = t + 256 * i;
            int r = c >> 3, kc = c & 7;
            const float4 v = *(const float4*)&A[(size_t)(m0 + r) * 1024 + k0 + kc * 4];
            ushort_t* d = &As[r * LDK + kc * 4];
            d[0] = f2bf(v.x); d[1] = f2bf(v.y); d[2] = f2bf(v.z); d[3] = f2bf(v.w);
        }
#pragma unroll
        for (int i = 0; i < 2; i++) {
            int c = t + 256 * i;
            int r = c >> 2, kc = c & 3;
            *(bf16x8*)&Bs[r * LDK + kc * 8] =
                *(const bf16x8*)&Wt[(size_t)(n0 + r) * 1024 + k0 + kc * 8];
        }
        __syncthreads();

        bf16x8 a[4], b[4];
#pragma unroll
        for (int i = 0; i < 4; i++)
            a[i] = *(const bf16x8*)&As[(wm + i * 16 + lrow) * LDK + lk];
#pragma unroll
        for (int j = 0; j < 4; j++)
            b[j] = *(const bf16x8*)&Bs[(wn + j * 16 + lrow) * LDK + lk];
#pragma unroll
        for (int i = 0; i < 4; i++)
#pragma unroll
            for (int j = 0; j < 4; j++)
                acc[i][j] = __builtin_amdgcn_mfma_f32_16x16x32_bf16(a[i], b[j], acc[i][j], 0, 0, 0);
    }

    int g = n0 >> 10;
    const float* bias = biases.p[g];
    int cg0 = (n0 & 1023) + wn;
#pragma unroll
    for (int j = 0; j < 4; j++) {
        int coln = n0 + wn + j * 16 + lrow;
        float bv = bias[cg0 + j * 16 + lrow];
#pragma unroll
        for (int i = 0; i < 4; i++) {
#pragma unroll
            for (int r = 0; r < 4; r++) {
                int rowm = m0 + wm + i * 16 + quad * 4 + r;
                G[(size_t)rowm * 4096 + coln] = f2bf(acc[i][j][r] + bv);
            }
        }
    }
}

// ---------------------------------------------------------------------------
// Init state + zero barrier flags (fresh per kernel_launch / per graph replay)
// ---------------------------------------------------------------------------
__global__ __launch_bounds__(256) void init_state(
    const float* __restrict__ h0, const float* __restrict__ c0,
    float* __restrict__ hf, float* __restrict__ cf, ushort_t* __restrict__ hb,
    unsigned* __restrict__ flags)
{
    int i = blockIdx.x * 256 + threadIdx.x;  // 65536
    float h = h0[i];
    hf[i] = h;
    cf[i] = c0[i];
    hb[i] = f2bf(h);
    if (blockIdx.x == 0 && threadIdx.x < NWG) flags[threadIdx.x] = 0;
}

// ---------------------------------------------------------------------------
// Persistent per-chunk recurrence kernel: 32 timesteps in ONE launch.
//   128 WGs x 256 thr (4 waves), 1 WG/CU (LDS-bound) -> all co-resident.
//   WG wg owns hidden units [wg*8, wg*8+8) = 32 gate-columns (vc = g*8+u).
//   W_h slice resident in LDS (staged once, XOR-swizzled).
//   h (bf16) staged per step in 4 quarter-buffers via pre-swizzled-source
//   global_load_lds, double-buffered (stage q+1 overlaps compute q).
//   c / h_fp32 / retention live in registers for the whole chunk.
//   Grid barrier: per-WG flag array, monotonic targets; threadfence release
//   (wbL2 flushes dirty hb) before arrive, threadfence acquire (inv) after.
// ---------------------------------------------------------------------------
__device__ __forceinline__ void stage_q(const ushort_t* __restrict__ hb_in,
                                        char* buf, int q, int wave, int lane) {
    // per wave: 8 KiB of the 32 KiB quarter, 8 x global_load_lds_dwordx4.
    // LDS dest linear (wave-uniform base + lane*16); SOURCE pre-inverse-swizzled
    // so that LDS byte (b*512 + k*2) ^ ((b&7)<<4) holds hb_in[b][q*256 + k].
#pragma unroll
    for (int j = 0; j < 8; j++) {
        int dbase = wave * 8192 + j * 1024;
        int d = dbase + lane * 16;
        int b = d >> 9;
        int off = (d & 511) ^ ((b & 7) << 4);
        const ushort_t* src = hb_in + (size_t)b * 1024 + q * 256 + (off >> 1);
        __builtin_amdgcn_global_load_lds(
            (const __attribute__((address_space(1))) unsigned int*)src,
            (__attribute__((address_space(3))) unsigned int*)(buf + dbase),
            16, 0, 0);
    }
}

__global__ __launch_bounds__(256, 1) void lstm_chunk(
    const ushort_t* __restrict__ WtH,   // bf16 [4][1024 n][1024 k]
    const ushort_t* __restrict__ Gc,    // bf16 chunk gates [2048 m][4096 n']
    const float* __restrict__ ret,      // fp32 [1024]
    float* __restrict__ cf_g,           // fp32 [64][1024] (chunk-boundary state)
    float* __restrict__ hf_g,           // fp32 [64][1024] (chunk-boundary state)
    ushort_t* __restrict__ hb0,         // bf16 h ping
    ushort_t* __restrict__ hb1,         // bf16 h pong
    float* __restrict__ out,            // d_out fp32
    unsigned* __restrict__ flags,       // [NWG] barrier flags (monotonic)
    int c)                              // chunk index
{
    extern __shared__ char smem[];
    char* Ws  = smem;                                   // 64 KiB
    char* Hq0 = smem + WS_BYTES;                        // 32 KiB
    char* Hq1 = smem + WS_BYTES + HQ_BYTES;             // 32 KiB
    float* S  = (float*)(smem + WS_BYTES + 2 * HQ_BYTES);          // 18 KiB
    ushort_t* Gg = (ushort_t*)(smem + WS_BYTES + 2 * HQ_BYTES + S_BYTES); // 4 KiB

    const int tid = threadIdx.x;
    const int wg = blockIdx.x;
    const int u0 = wg * 8;
    const int wave = tid >> 6, lane = tid & 63;
    const int lrow = lane & 15, quad = lane >> 4;
    const int mh = (wave & 1) * 32;     // batch-half base (rows)
    const int kg = wave >> 1;           // k-group (0/1) within each quarter
    const int swz = (lrow & 7) << 4;    // shared XOR term (rows/cols = lrow mod 8)

    // ---- stage W_h slice into LDS once (swizzled dest) ----
#pragma unroll
    for (int rr = 0; rr < 16; rr++) {
        int idx = tid + rr * 256;          // 16B-slot id, 4096 slots
        int vc = idx >> 7;                 // 128 slots per 2048-B row
        int kb = (idx & 127) * 16;         // byte offset within row
        const ushort_t* src = WtH + (size_t)(vc >> 3) * 1048576
                                  + (size_t)(u0 + (vc & 7)) * 1024 + (kb >> 1);
        bf16x8 v = *(const bf16x8*)src;
        *(bf16x8*)(Ws + ((vc * 2048 + kb) ^ ((vc & 7) << 4))) = v;
    }

    // ---- load persistent state into registers (2 (b,u) pairs per thread) ----
    float hf_r[2], cf_r[2], ret_r[2];
    int idx_r[2];
#pragma unroll
    for (int i = 0; i < 2; i++) {
        int lin = tid + i * 256;
        int b = lin >> 3, u = lin & 7;
        int idx = b * 1024 + u0 + u;
        idx_r[i] = idx;
        hf_r[i] = hf_g[idx];
        cf_r[i] = cf_g[idx];
        ret_r[i] = ret[u0 + u];
    }
    __syncthreads();

    const unsigned tbase = (unsigned)c * (unsigned)(CHUNK - 1);

#pragma unroll 1
    for (int tc = 0; tc < CHUNK; tc++) {
        const int t = c * CHUNK + tc;
        const ushort_t* hb_in = (tc & 1) ? hb1 : hb0;
        ushort_t* hb_out      = (tc & 1) ? hb0 : hb1;

        // gate-precompute prefetch: thread -> (b=tid>>2, gate=tid&3), 8 units
        uint4 gpre;
        {
            int b = tid >> 2, g = tid & 3;
            gpre = *(const uint4*)(Gc + ((size_t)(tc * 64 + b)) * 4096 + g * 1024 + u0);
        }

        // stage quarter 0, then pipelined quarters with double buffer
        stage_q(hb_in, Hq0, 0, wave, lane);
        asm volatile("s_waitcnt vmcnt(0)" ::: "memory");
        __syncthreads();

        f32x4 acc[2][2] = {};
#pragma unroll
        for (int q = 0; q < 4; q++) {
            if (q < 3) stage_q(hb_in, ((q & 1) == 0) ? Hq1 : Hq0, q + 1, wave, lane);
            char* hbuf = ((q & 1) == 0) ? Hq0 : Hq1;
#pragma unroll
            for (int i = 0; i < 4; i++) {
                int kl = kg * 128 + i * 32 + quad * 8;    // k within quarter
                int kgl = q * 256 + kl;                    // global k
                bf16x8 a0 = *(const bf16x8*)(hbuf + (((mh + lrow) * 512 + kl * 2) ^ swz));
                bf16x8 a1 = *(const bf16x8*)(hbuf + (((mh + 16 + lrow) * 512 + kl * 2) ^ swz));
                bf16x8 b0 = *(const bf16x8*)(Ws + ((lrow * 2048 + kgl * 2) ^ swz));
                bf16x8 b1 = *(const bf16x8*)(Ws + (((lrow + 16) * 2048 + kgl * 2) ^ swz));
                acc[0][0] = __builtin_amdgcn_mfma_f32_16x16x32_bf16(a0, b0, acc[0][0], 0, 0, 0);
                acc[0][1] = __builtin_amdgcn_mfma_f32_16x16x32_bf16(a0, b1, acc[0][1], 0, 0, 0);
                acc[1][0] = __builtin_amdgcn_mfma_f32_16x16x32_bf16(a1, b0, acc[1][0], 0, 0, 0);
                acc[1][1] = __builtin_amdgcn_mfma_f32_16x16x32_bf16(a1, b1, acc[1][1], 0, 0, 0);
            }
            if (q < 3) asm volatile("s_waitcnt vmcnt(0)" ::: "memory");
            __syncthreads();
        }

        // write kg-partial S (C/D layout: col = lane&15, row = quad*4 + r)
#pragma unroll
        for (int m = 0; m < 2; m++)
#pragma unroll
            for (int n = 0; n < 2; n++)
#pragma unroll
                for (int r = 0; r < 4; r++)
                    S[kg * 64 * S_STRIDE + (mh + m * 16 + quad * 4 + r) * S_STRIDE
                      + n * 16 + lrow] = acc[m][n][r];
        // park gate-precompute in LDS for the elementwise redistribution
        {
            int b = tid >> 2, g = tid & 3;
            *(uint4*)&Gg[b * 32 + g * 8] = gpre;
        }
        __syncthreads();

        // ---- elementwise LSTM + retention blend (register state) ----
#pragma unroll
        for (int i = 0; i < 2; i++) {
            int lin = tid + i * 256;
            int b = lin >> 3, u = lin & 7;
            int brow = b * S_STRIDE;
            float si = S[brow + u]      + S[64 * S_STRIDE + brow + u]      + bf2f(Gg[b * 32 + u]);
            float sf = S[brow + 8 + u]  + S[64 * S_STRIDE + brow + 8 + u]  + bf2f(Gg[b * 32 + 8 + u]);
            float so = S[brow + 16 + u] + S[64 * S_STRIDE + brow + 16 + u] + bf2f(Gg[b * 32 + 16 + u]);
            float sc = S[brow + 24 + u] + S[64 * S_STRIDE + brow + 24 + u] + bf2f(Gg[b * 32 + 24 + u]);
            float it = 1.f / (1.f + __expf(-si));
            float ft = 1.f / (1.f + __expf(-sf));
            float ot = 1.f / (1.f + __expf(-so));
            float gt = 1.f - 2.f / (__expf(2.f * sc) + 1.f);   // NaN-safe tanh
            float cn = cf_r[i] * ft + it * gt;
            float tcn = 1.f - 2.f / (__expf(2.f * cn) + 1.f);  // NaN-safe tanh
            float hl = ot * tcn;
            float rr = ret_r[i];
            float hn = rr * hf_r[i] + (1.f - rr) * hl;
            cf_r[i] = cn;
            hf_r[i] = hn;
            hb_out[idx_r[i]] = f2bf(hn);
            __builtin_nontemporal_store(hn, &out[(size_t)t * 65536 + idx_r[i]]);
        }

        // ---- grid barrier between steps (skip after last: kernel end syncs) ----
        if (tc < CHUNK - 1) {
            __syncthreads();          // all waves' stores vmcnt-drained
            __threadfence();          // release: wbL2 (dirty hb) to coherent point
            __syncthreads();          // all waves' flushes complete before arrive
            unsigned target = tbase + (unsigned)tc + 1u;
            if (tid == 0)
                __hip_atomic_store(&flags[wg], target, __ATOMIC_RELAXED,
                                   __HIP_MEMORY_SCOPE_AGENT);
            if (tid < NWG)
                while (__hip_atomic_load(&flags[tid], __ATOMIC_RELAXED,
                                         __HIP_MEMORY_SCOPE_AGENT) < target) {}
            __syncthreads();
            __threadfence();          // acquire: inv stale L1/L2 before next h read
        }
    }

    // ---- write back chunk-boundary state ----
#pragma unroll
    for (int i = 0; i < 2; i++) {
        hf_g[idx_r[i]] = hf_r[i];
        cf_g[idx_r[i]] = cf_r[i];
    }
}

// ---------------------------------------------------------------------------
// Epilogue: append h_T and c_T (fp32) to d_out
// ---------------------------------------------------------------------------
__global__ __launch_bounds__(256) void epilogue_k(
    const float* __restrict__ hf_final, const float* __restrict__ cf,
    float* __restrict__ out)
{
    int i = blockIdx.x * 256 + threadIdx.x;  // 65536
    out[OUTS_ELEMS + i] = hf_final[i];
    out[OUTS_ELEMS + 65536 + i] = cf[i];
}

// ---------------------------------------------------------------------------
extern "C" void kernel_launch(void* const* d_in, const int* in_sizes, int n_in,
                              void* d_out, int out_size, void* d_ws, size_t ws_size,
                              hipStream_t stream)
{
    const float* input_ = (const float*)d_in[0];
    const float* h0   = (const float*)d_in[1];
    const float* c0   = (const float*)d_in[2];
    const float* w_xi = (const float*)d_in[3];
    const float* w_xf = (const float*)d_in[4];
    const float* w_xo = (const float*)d_in[5];
    const float* w_xc = (const float*)d_in[6];
    const float* w_hi = (const float*)d_in[7];
    const float* w_hf = (const float*)d_in[8];
    const float* w_ho = (const float*)d_in[9];
    const float* w_hc = (const float*)d_in[10];
    const float* b_i  = (const float*)d_in[11];
    const float* b_f  = (const float*)d_in[12];
    const float* b_o  = (const float*)d_in[13];
    const float* b_c  = (const float*)d_in[14];
    const float* ret  = (const float*)d_in[15];

    // workspace carve (~33.6 MiB)
    ushort_t* wt_x   = (ushort_t*)d_ws;            // 4*1M bf16  (8 MiB)
    ushort_t* wt_h   = wt_x + 4ULL * 1048576;      // 4*1M bf16  (8 MiB)
    ushort_t* gchunk = wt_h + 4ULL * 1048576;      // 2048*4096 bf16 (16 MiB)
    float*  cf  = (float*)(gchunk + (size_t)MCH * 4096);
    float*  hf0 = cf + 65536;
    float*  hf1 = hf0 + 65536;                     // (unused; carve kept stable)
    ushort_t* hb0 = (ushort_t*)(hf1 + 65536);
    ushort_t* hb1 = hb0 + 65536;
    unsigned* flags = (unsigned*)(hb1 + 65536);    // NWG barrier flags (512 B)
    float* out = (float*)d_out;

    static bool attr_set = false;
    if (!attr_set) {
        hipFuncSetAttribute(reinterpret_cast<const void*>(lstm_chunk),
                            hipFuncAttributeMaxDynamicSharedMemorySize, SMEM_BYTES);
        attr_set = true;
    }

    Ptr8 p8; p8.p[0] = w_xi; p8.p[1] = w_xf; p8.p[2] = w_xo; p8.p[3] = w_xc;
             p8.p[4] = w_hi; p8.p[5] = w_hf; p8.p[6] = w_ho; p8.p[7] = w_hc;
    transpose8<<<dim3(16, 16, 8), 256, 0, stream>>>(p8, wt_x);

    init_state<<<256, 256, 0, stream>>>(h0, c0, hf0, cf, hb0, flags);

    Ptr4 b4; b4.p[0] = b_i; b4.p[1] = b_f; b4.p[2] = b_o; b4.p[3] = b_c;

    for (int chunk = 0; chunk < NCHUNK; chunk++) {
        chunk_gemm<<<dim3(32, 16), 256, 0, stream>>>(
            input_ + (size_t)chunk * MCH * 1024, wt_x, b4, gchunk);
        lstm_chunk<<<NWG, 256, SMEM_BYTES, stream>>>(
            wt_h, gchunk, ret, cf, hf0, hb0, hb1, out, flags, chunk);
    }

    epilogue_k<<<256, 256, 0, stream>>>(hf0, cf, out);
}

// Round 2
// 5070.251 us; speedup vs baseline: 2.4303x; 2.4303x over previous
//
#include <hip/hip_runtime.h>

typedef unsigned short ushort_t;
typedef __bf16 bf16x8 __attribute__((ext_vector_type(8)));
typedef float f32x4 __attribute__((ext_vector_type(4)));
typedef unsigned int u32x4 __attribute__((ext_vector_type(4)));

#define T_STEPS 512
#define BATCH 64
#define HDIM 1024
#define CHUNK 32                 // steps per gate-precompute chunk
#define NCHUNK (T_STEPS / CHUNK) // 16
#define MCH (CHUNK * BATCH)      // 2048 rows per chunk GEMM
#define OUTS_ELEMS 33554432ULL
#define NWG 128                  // persistent WGs; 1/CU by LDS => co-residency guaranteed

// ---- LDS carve for lstm_chunk (dynamic) ----
#define WS_BYTES   65536                       // W_h slice: 32 vc x 1024 k bf16, XOR-swizzled
#define HQ_BYTES   32768                       // h quarter: 64 b x 256 k bf16, XOR-swizzled
#define S_STRIDE   36                          // padded fp32 row stride
#define S_BYTES    (2 * 64 * S_STRIDE * 4)     // 18432
#define GG_BYTES   (64 * 32 * 2)               // 4096
#define HW_BYTES   (64 * 8 * 2)                // 1024: gathered h-out tile
#define SMEM_BYTES (WS_BYTES + 2 * HQ_BYTES + S_BYTES + GG_BYTES + HW_BYTES) // 154624

// ---- coherent (LLC-level, cross-XCD) 16B access: sc0 sc1 bypass L1+L2 ----
#define GLOAD16_COH(dst, src) \
    asm volatile("global_load_dwordx4 %0, %1, off sc0 sc1" : "=v"(dst) : "v"(src) : "memory")
#define GLOAD16_CACHED(dst, src) \
    asm volatile("global_load_dwordx4 %0, %1, off" : "=v"(dst) : "v"(src) : "memory")
#define GSTORE16_COH(dst, val) \
    asm volatile("global_store_dwordx4 %0, %1, off sc0 sc1" :: "v"(dst), "v"(val) : "memory")
// counted vmcnt wait, register-tied so consumers can't be hoisted above it
#define WAITVM(N, R) \
    asm volatile("s_waitcnt vmcnt(" #N ")" \
        : "+v"(R[0]), "+v"(R[1]), "+v"(R[2]), "+v"(R[3]), \
          "+v"(R[4]), "+v"(R[5]), "+v"(R[6]), "+v"(R[7]) :: "memory")
// raw workgroup barrier: LDS-visibility only, does NOT drain vmcnt (keeps loads in flight)
#define WGBAR() do { asm volatile("s_waitcnt lgkmcnt(0)" ::: "memory"); \
                     __builtin_amdgcn_s_barrier(); } while (0)

__device__ __forceinline__ ushort_t f2bf(float f) {
    union { unsigned int i; float f; } v;
    v.f = f;
    unsigned int x = v.i;
    unsigned int r = (x + 0x7FFFu + ((x >> 16) & 1u)) >> 16;
    return (ushort_t)r;
}

__device__ __forceinline__ float bf2f(ushort_t u) {
    union { unsigned int i; float f; } v;
    v.i = ((unsigned int)u) << 16;
    return v.f;
}

struct Ptr8 { const float* p[8]; };
struct Ptr4 { const float* p[4]; };

// ---------------------------------------------------------------------------
// Transpose+convert 8 fp32 weight matrices [1024 k][1024 n] -> bf16 [1024 n][1024 k]
// ---------------------------------------------------------------------------
__global__ __launch_bounds__(256) void transpose8(Ptr8 in, ushort_t* __restrict__ out) {
    __shared__ ushort_t tile[64][65];
    int z = blockIdx.z;
    const float* src = in.p[z];
    ushort_t* dst = out + (size_t)z * 1024 * 1024;
    int bx = blockIdx.x * 64;  // n base
    int by = blockIdx.y * 64;  // k base
    int t = threadIdx.x;
#pragma unroll
    for (int i = 0; i < 16; i++) {
        int lin = t + i * 256;
        int r = lin >> 6, c = lin & 63;
        tile[r][c] = f2bf(src[(size_t)(by + r) * 1024 + bx + c]);
    }
    __syncthreads();
#pragma unroll
    for (int i = 0; i < 16; i++) {
        int lin = t + i * 256;
        int r = lin >> 6, c = lin & 63;
        dst[(size_t)(bx + r) * 1024 + by + c] = tile[c][r];
    }
}

// ---------------------------------------------------------------------------
// Chunk GEMM: G[m][n'] = A[m][:] @ wt_x[n'][:] + bias   (fp32 acc, bf16 out)
// ---------------------------------------------------------------------------
#define BK 32
#define LDK 40

__global__ __launch_bounds__(256) void chunk_gemm(
    const float* __restrict__ A,
    const ushort_t* __restrict__ Wt,
    Ptr4 biases,
    ushort_t* __restrict__ G)            // [2048 m][4096 n']
{
    __shared__ ushort_t As[128 * LDK];
    __shared__ ushort_t Bs[128 * LDK];

    int n0 = blockIdx.x * 128;
    int m0 = blockIdx.y * 128;
    int t = threadIdx.x;
    int wave = t >> 6, lane = t & 63;
    int wm = (wave & 1) * 64, wn = (wave >> 1) * 64;
    int lrow = lane & 15, quad = lane >> 4;
    int lk = quad * 8;

    f32x4 acc[4][4] = {};

    for (int k0 = 0; k0 < 1024; k0 += BK) {
        __syncthreads();
#pragma unroll
        for (int i = 0; i < 4; i++) {
            int c = t + 256 * i;
            int r = c >> 3, kc = c & 7;
            const float4 v = *(const float4*)&A[(size_t)(m0 + r) * 1024 + k0 + kc * 4];
            ushort_t* d = &As[r * LDK + kc * 4];
            d[0] = f2bf(v.x); d[1] = f2bf(v.y); d[2] = f2bf(v.z); d[3] = f2bf(v.w);
        }
#pragma unroll
        for (int i = 0; i < 2; i++) {
            int c = t + 256 * i;
            int r = c >> 2, kc = c & 3;
            *(bf16x8*)&Bs[r * LDK + kc * 8] =
                *(const bf16x8*)&Wt[(size_t)(n0 + r) * 1024 + k0 + kc * 8];
        }
        __syncthreads();

        bf16x8 a[4], b[4];
#pragma unroll
        for (int i = 0; i < 4; i++)
            a[i] = *(const bf16x8*)&As[(wm + i * 16 + lrow) * LDK + lk];
#pragma unroll
        for (int j = 0; j < 4; j++)
            b[j] = *(const bf16x8*)&Bs[(wn + j * 16 + lrow) * LDK + lk];
#pragma unroll
        for (int i = 0; i < 4; i++)
#pragma unroll
            for (int j = 0; j < 4; j++)
                acc[i][j] = __builtin_amdgcn_mfma_f32_16x16x32_bf16(a[i], b[j], acc[i][j], 0, 0, 0);
    }

    int g = n0 >> 10;
    const float* bias = biases.p[g];
    int cg0 = (n0 & 1023) + wn;
#pragma unroll
    for (int j = 0; j < 4; j++) {
        int coln = n0 + wn + j * 16 + lrow;
        float bv = bias[cg0 + j * 16 + lrow];
#pragma unroll
        for (int i = 0; i < 4; i++) {
#pragma unroll
            for (int r = 0; r < 4; r++) {
                int rowm = m0 + wm + i * 16 + quad * 4 + r;
                G[(size_t)rowm * 4096 + coln] = f2bf(acc[i][j][r] + bv);
            }
        }
    }
}

// ---------------------------------------------------------------------------
// Init state + zero barrier flags (fresh per launch / graph replay)
// ---------------------------------------------------------------------------
__global__ __launch_bounds__(256) void init_state(
    const float* __restrict__ h0, const float* __restrict__ c0,
    float* __restrict__ hf, float* __restrict__ cf, ushort_t* __restrict__ hb,
    unsigned* __restrict__ flags)
{
    int i = blockIdx.x * 256 + threadIdx.x;  // 65536
    float h = h0[i];
    hf[i] = h;
    cf[i] = c0[i];
    hb[i] = f2bf(h);
    if (blockIdx.x == 0 && threadIdx.x < NWG) flags[threadIdx.x] = 0;
}

// ---------------------------------------------------------------------------
// Persistent per-chunk recurrence kernel: 32 timesteps in ONE launch.
//   Coherence via sc0/sc1 per-access flags (LLC-level), NOT threadfence:
//   no buffer_wbl2/inv, no L2 blowouts. Grid barrier = per-WG flag array.
// ---------------------------------------------------------------------------
__device__ __forceinline__ void qload(const ushort_t* __restrict__ hb_in, int q,
                                      int tid, u32x4 (&R)[8]) {
    // quarter q = 64 b x 256 k bf16 (32 KiB). slot s (16B) -> b = s>>5, k = (s&31)*8
#pragma unroll
    for (int j = 0; j < 8; j++) {
        int s = tid + j * 256;
        const ushort_t* src = hb_in + (size_t)(s >> 5) * 1024 + q * 256 + ((s & 31) << 3);
        GLOAD16_COH(R[j], src);
    }
}

__device__ __forceinline__ void qwrite(char* buf, int tid, u32x4 (&R)[8]) {
    // LDS byte (b*512 + k*2) ^ ((b&7)<<4)  ==  (s*16) ^ (((s>>5)&7)<<4)
#pragma unroll
    for (int j = 0; j < 8; j++) {
        int s = tid + j * 256;
        *(u32x4*)(buf + ((s * 16) ^ (((s >> 5) & 7) << 4))) = R[j];
    }
}

__device__ __forceinline__ void computeQ(const char* hbuf, const char* Ws, int q,
        int mh, int kg, int lrow, int quad, int swz, f32x4 (&acc)[2][2]) {
#pragma unroll
    for (int i = 0; i < 4; i++) {
        int kl = kg * 128 + i * 32 + quad * 8;     // k within quarter
        int kgl = q * 256 + kl;                    // global k
        bf16x8 a0 = *(const bf16x8*)(hbuf + (((mh + lrow) * 512 + kl * 2) ^ swz));
        bf16x8 a1 = *(const bf16x8*)(hbuf + (((mh + 16 + lrow) * 512 + kl * 2) ^ swz));
        bf16x8 b0 = *(const bf16x8*)(Ws + ((lrow * 2048 + kgl * 2) ^ swz));
        bf16x8 b1 = *(const bf16x8*)(Ws + (((lrow + 16) * 2048 + kgl * 2) ^ swz));
        acc[0][0] = __builtin_amdgcn_mfma_f32_16x16x32_bf16(a0, b0, acc[0][0], 0, 0, 0);
        acc[0][1] = __builtin_amdgcn_mfma_f32_16x16x32_bf16(a0, b1, acc[0][1], 0, 0, 0);
        acc[1][0] = __builtin_amdgcn_mfma_f32_16x16x32_bf16(a1, b0, acc[1][0], 0, 0, 0);
        acc[1][1] = __builtin_amdgcn_mfma_f32_16x16x32_bf16(a1, b1, acc[1][1], 0, 0, 0);
    }
}

__global__ __launch_bounds__(256, 1) void lstm_chunk(
    const ushort_t* __restrict__ WtH,   // bf16 [4][1024 n][1024 k]
    const ushort_t* __restrict__ Gc,    // bf16 chunk gates [2048 m][4096 n']
    const float* __restrict__ ret,      // fp32 [1024]
    float* __restrict__ cf_g,           // fp32 chunk-boundary state
    float* __restrict__ hf_g,           // fp32 chunk-boundary state
    ushort_t* __restrict__ hb0,         // bf16 h ping
    ushort_t* __restrict__ hb1,         // bf16 h pong
    float* __restrict__ out,            // d_out fp32
    unsigned* __restrict__ flags,       // [NWG] barrier flags (monotonic)
    int c)                              // chunk index
{
    extern __shared__ char smem[];
    char* Ws  = smem;                                             // 64 KiB
    char* Hq0 = smem + WS_BYTES;                                  // 32 KiB
    char* Hq1 = smem + WS_BYTES + HQ_BYTES;                       // 32 KiB
    float* S  = (float*)(smem + WS_BYTES + 2 * HQ_BYTES);         // 18 KiB
    ushort_t* Gg = (ushort_t*)(smem + WS_BYTES + 2 * HQ_BYTES + S_BYTES);            // 4 KiB
    ushort_t* Hw = (ushort_t*)(smem + WS_BYTES + 2 * HQ_BYTES + S_BYTES + GG_BYTES); // 1 KiB

    const int tid = threadIdx.x;
    const int wg = blockIdx.x;
    const int u0 = wg * 8;
    const int wave = tid >> 6, lane = tid & 63;
    const int lrow = lane & 15, quad = lane >> 4;
    const int mh = (wave & 1) * 32;     // batch-half base (rows)
    const int kg = wave >> 1;           // k-group (0/1) within each quarter
    const int swz = (lrow & 7) << 4;    // shared XOR swizzle term

    (void)wave; (void)lane;

    // ---- stage W_h slice into LDS once (swizzled dest), cached loads ----
#pragma unroll
    for (int rr = 0; rr < 16; rr++) {
        int idx = tid + rr * 256;          // 16B-slot id, 4096 slots
        int vc = idx >> 7;                 // 128 slots per 2048-B row
        int kb = (idx & 127) * 16;         // byte offset within row
        const ushort_t* src = WtH + (size_t)(vc >> 3) * 1048576
                                  + (size_t)(u0 + (vc & 7)) * 1024 + (kb >> 1);
        bf16x8 v = *(const bf16x8*)src;
        *(bf16x8*)(Ws + ((vc * 2048 + kb) ^ ((vc & 7) << 4))) = v;
    }

    // ---- persistent state in registers (2 (b,u) pairs per thread) ----
    float hf_r[2], cf_r[2], ret_r[2];
    int idx_r[2];
#pragma unroll
    for (int i = 0; i < 2; i++) {
        int lin = tid + i * 256;
        int b = lin >> 3, u = lin & 7;
        int idx = b * 1024 + u0 + u;
        idx_r[i] = idx;
        hf_r[i] = hf_g[idx];
        cf_r[i] = cf_g[idx];
        ret_r[i] = ret[u0 + u];
    }
    // pin: forces the compiler to insert its waitcnt for the state loads HERE,
    // so no compiler-tracked VM loads remain outstanding inside the step loop.
    asm volatile("" :: "v"(hf_r[0]), "v"(hf_r[1]), "v"(cf_r[0]), "v"(cf_r[1]),
                       "v"(ret_r[0]), "v"(ret_r[1]));
    __syncthreads();
    asm volatile("s_waitcnt vmcnt(0)" ::: "memory");

    const unsigned tbase = (unsigned)c * (unsigned)(CHUNK - 1);

#pragma unroll 1
    for (int tc = 0; tc < CHUNK; tc++) {
        const int t = c * CHUNK + tc;
        const ushort_t* hb_in = (tc & 1) ? hb1 : hb0;
        ushort_t* hb_out      = (tc & 1) ? hb0 : hb1;

        // gate-precompute prefetch (oldest outstanding VM op, asm-tracked)
        u32x4 gpre;
        {
            int b = tid >> 2, g = tid & 3;
            const ushort_t* gp = Gc + ((size_t)(tc * 64 + b)) * 4096 + g * 1024 + u0;
            GLOAD16_CACHED(gpre, gp);
        }

        // issue ALL FOUR quarters' coherent loads up-front (32 x 16B per thread)
        u32x4 R0[8], R1[8], R2[8], R3[8];
        qload(hb_in, 0, tid, R0);
        qload(hb_in, 1, tid, R1);
        qload(hb_in, 2, tid, R2);
        qload(hb_in, 3, tid, R3);
        // outstanding: gpre(1) + 32 loads. vmcnt(24) -> gpre+R0 complete.
        WAITVM(24, R0);
        qwrite(Hq0, tid, R0);
        WGBAR();

        f32x4 acc[2][2] = {};
        computeQ(Hq0, Ws, 0, mh, kg, lrow, quad, swz, acc);
        WAITVM(16, R1);
        qwrite(Hq1, tid, R1);
        WGBAR();

        computeQ(Hq1, Ws, 1, mh, kg, lrow, quad, swz, acc);
        WAITVM(8, R2);
        qwrite(Hq0, tid, R2);
        WGBAR();

        computeQ(Hq0, Ws, 2, mh, kg, lrow, quad, swz, acc);
        WAITVM(0, R3);
        qwrite(Hq1, tid, R3);
        WGBAR();

        computeQ(Hq1, Ws, 3, mh, kg, lrow, quad, swz, acc);

        // write kg-partial S (C/D layout: col = lane&15, row = quad*4 + r)
#pragma unroll
        for (int m = 0; m < 2; m++)
#pragma unroll
            for (int n = 0; n < 2; n++)
#pragma unroll
                for (int r = 0; r < 4; r++)
                    S[kg * 64 * S_STRIDE + (mh + m * 16 + quad * 4 + r) * S_STRIDE
                      + n * 16 + lrow] = acc[m][n][r];
        // park gate-precompute in LDS
        {
            int b = tid >> 2, g = tid & 3;
            *(u32x4*)&Gg[b * 32 + g * 8] = gpre;
        }
        WGBAR();

        // ---- elementwise LSTM + retention blend (register state) ----
#pragma unroll
        for (int i = 0; i < 2; i++) {
            int lin = tid + i * 256;
            int b = lin >> 3, u = lin & 7;
            int brow = b * S_STRIDE;
            float si = S[brow + u]      + S[64 * S_STRIDE + brow + u]      + bf2f(Gg[b * 32 + u]);
            float sf = S[brow + 8 + u]  + S[64 * S_STRIDE + brow + 8 + u]  + bf2f(Gg[b * 32 + 8 + u]);
            float so = S[brow + 16 + u] + S[64 * S_STRIDE + brow + 16 + u] + bf2f(Gg[b * 32 + 16 + u]);
            float sc = S[brow + 24 + u] + S[64 * S_STRIDE + brow + 24 + u] + bf2f(Gg[b * 32 + 24 + u]);
            float it = 1.f / (1.f + __expf(-si));
            float ft = 1.f / (1.f + __expf(-sf));
            float ot = 1.f / (1.f + __expf(-so));
            float gt = 1.f - 2.f / (__expf(2.f * sc) + 1.f);   // NaN-safe tanh
            float cn = cf_r[i] * ft + it * gt;
            float tcn = 1.f - 2.f / (__expf(2.f * cn) + 1.f);  // NaN-safe tanh
            float hl = ot * tcn;
            float rr = ret_r[i];
            float hn = rr * hf_r[i] + (1.f - rr) * hl;
            cf_r[i] = cn;
            hf_r[i] = hn;
            Hw[lin] = f2bf(hn);                                // gather for coherent store
            __builtin_nontemporal_store(hn, &out[(size_t)t * 65536 + idx_r[i]]);
        }
        WGBAR();   // Hw visible

        // gathered coherent h-out store: 64 x 16B (batch-row b = tid, units u0..u0+7)
        if (tid < 64) {
            u32x4 v = *(const u32x4*)&Hw[tid * 8];
            ushort_t* dst = hb_out + (size_t)tid * 1024 + u0;
            GSTORE16_COH(dst, v);
            // write-through stores acked at coherent point once vmcnt==0
            asm volatile("s_waitcnt vmcnt(0)" ::: "memory");
        }

        // ---- grid barrier between steps (skip after last) ----
        if (tc < CHUNK - 1) {
            unsigned target = tbase + (unsigned)tc + 1u;
            if (tid == 0)
                __hip_atomic_store(&flags[wg], target, __ATOMIC_RELAXED,
                                   __HIP_MEMORY_SCOPE_AGENT);
            if (tid < NWG)
                while (__hip_atomic_load(&flags[tid], __ATOMIC_RELAXED,
                                         __HIP_MEMORY_SCOPE_AGENT) < target) {}
            WGBAR();
            asm volatile("s_waitcnt vmcnt(0)" ::: "memory");  // poll loads drained
        }
    }

    // ---- write back chunk-boundary state (normal stores; dispatch-end release) ----
#pragma unroll
    for (int i = 0; i < 2; i++) {
        hf_g[idx_r[i]] = hf_r[i];
        cf_g[idx_r[i]] = cf_r[i];
    }
}

// ---------------------------------------------------------------------------
// Epilogue: append h_T and c_T (fp32) to d_out
// ---------------------------------------------------------------------------
__global__ __launch_bounds__(256) void epilogue_k(
    const float* __restrict__ hf_final, const float* __restrict__ cf,
    float* __restrict__ out)
{
    int i = blockIdx.x * 256 + threadIdx.x;  // 65536
    out[OUTS_ELEMS + i] = hf_final[i];
    out[OUTS_ELEMS + 65536 + i] = cf[i];
}

// ---------------------------------------------------------------------------
extern "C" void kernel_launch(void* const* d_in, const int* in_sizes, int n_in,
                              void* d_out, int out_size, void* d_ws, size_t ws_size,
                              hipStream_t stream)
{
    const float* input_ = (const float*)d_in[0];
    const float* h0   = (const float*)d_in[1];
    const float* c0   = (const float*)d_in[2];
    const float* w_xi = (const float*)d_in[3];
    const float* w_xf = (const float*)d_in[4];
    const float* w_xo = (const float*)d_in[5];
    const float* w_xc = (const float*)d_in[6];
    const float* w_hi = (const float*)d_in[7];
    const float* w_hf = (const float*)d_in[8];
    const float* w_ho = (const float*)d_in[9];
    const float* w_hc = (const float*)d_in[10];
    const float* b_i  = (const float*)d_in[11];
    const float* b_f  = (const float*)d_in[12];
    const float* b_o  = (const float*)d_in[13];
    const float* b_c  = (const float*)d_in[14];
    const float* ret  = (const float*)d_in[15];

    // workspace carve (~33.6 MiB)
    ushort_t* wt_x   = (ushort_t*)d_ws;            // 4*1M bf16  (8 MiB)
    ushort_t* wt_h   = wt_x + 4ULL * 1048576;      // 4*1M bf16  (8 MiB)
    ushort_t* gchunk = wt_h + 4ULL * 1048576;      // 2048*4096 bf16 (16 MiB)
    float*  cf  = (float*)(gchunk + (size_t)MCH * 4096);
    float*  hf0 = cf + 65536;
    float*  hf1 = hf0 + 65536;                     // (unused; carve kept stable)
    ushort_t* hb0 = (ushort_t*)(hf1 + 65536);
    ushort_t* hb1 = hb0 + 65536;
    unsigned* flags = (unsigned*)(hb1 + 65536);    // NWG barrier flags
    float* out = (float*)d_out;

    static bool attr_set = false;
    if (!attr_set) {
        hipFuncSetAttribute(reinterpret_cast<const void*>(lstm_chunk),
                            hipFuncAttributeMaxDynamicSharedMemorySize, SMEM_BYTES);
        attr_set = true;
    }

    Ptr8 p8; p8.p[0] = w_xi; p8.p[1] = w_xf; p8.p[2] = w_xo; p8.p[3] = w_xc;
             p8.p[4] = w_hi; p8.p[5] = w_hf; p8.p[6] = w_ho; p8.p[7] = w_hc;
    transpose8<<<dim3(16, 16, 8), 256, 0, stream>>>(p8, wt_x);

    init_state<<<256, 256, 0, stream>>>(h0, c0, hf0, cf, hb0, flags);

    Ptr4 b4; b4.p[0] = b_i; b4.p[1] = b_f; b4.p[2] = b_o; b4.p[3] = b_c;

    for (int chunk = 0; chunk < NCHUNK; chunk++) {
        chunk_gemm<<<dim3(32, 16), 256, 0, stream>>>(
            input_ + (size_t)chunk * MCH * 1024, wt_x, b4, gchunk);
        lstm_chunk<<<NWG, 256, SMEM_BYTES, stream>>>(
            wt_h, gchunk, ret, cf, hf0, hb0, hb1, out, flags, chunk);
    }

    epilogue_k<<<256, 256, 0, stream>>>(hf0, cf, out);
}